// Round 1
// 457.564 us; speedup vs baseline: 1.0321x; 1.0321x over previous
//
#include <hip/hip_runtime.h>
#include <math.h>

// DiffGatedTopK: x (16384 x 4096 fp32). Per row: k=614 top-k mask, gain =
// sigmoid(top1-top2)*3+1, out = x*mask*gain.
//
// One WAVE per row, row resident in registers as order-preserving uints
// (64/lane). Exact k-th-largest bit pattern via BRACKETED INTERPOLATION
// search: two probe counts at t=0.90 / t=1.17 are fused into the load pass
// (row thresholds are N(1.036, 0.024) for i.i.d. N(0,1) rows, so the bracket
// holds at ~5.5 sigma; if it misses, we fall back to the enclosing range --
// still exact). Inside the bracket, regula-falsi interpolation alternated
// with bisection converges to count==K in ~3-5 passes vs ~17-19 for pure
// 32-bit bisection, cutting the dominant VALU+SALU cost of the search.
// Exact-duplicate boundary ties fall to a rare ballot-rank path (lowest
// index first, matching jax.lax.top_k).
// No LDS, no atomics, no barriers. NT stores keep the L3-resident input hot.

#define D     4096
#define K     614            // int(4096 * 0.15)
#define BLOCK 256
#define VPT   64             // values per lane
#define NB    16             // float4 batches per lane

typedef float f32x4 __attribute__((ext_vector_type(4)));

__device__ __forceinline__ unsigned int f2ord(float f) {
    unsigned int b = __float_as_uint(f);
    return ((int)b >= 0) ? (b | 0x80000000u) : ~b;
}
__device__ __forceinline__ float ord2f(unsigned int u) {
    return __uint_as_float(((int)u < 0) ? (u ^ 0x80000000u) : ~u);
}

__global__ __launch_bounds__(BLOCK, 4)   // 128-VGPR cap: u[64]+temps fits, no spill
void diffgated_topk(const float* __restrict__ x, float* __restrict__ out, int rows) {
    const int lane = threadIdx.x & 63;
    const int wav  = threadIdx.x >> 6;
    const int row  = blockIdx.x * 4 + wav;
    if (row >= rows) return;                          // wave-uniform
    const f32x4* xrow = (const f32x4*)(x + (size_t)row * D);
    f32x4*       orow = (f32x4*)(out + (size_t)row * D);

    const unsigned int A = f2ord(0.90f);              // compile-time folds
    const unsigned int B = f2ord(1.17f);

    // ---- load row -> registers (ordered uints); fused per-lane top-2 and
    //      probe counts (values fresh in VGPRs: no AGPR re-read, no SALU) ----
    unsigned int u[VPT];
    unsigned int m1 = 0u, m2 = 0u;                    // ordered 0 == -inf
    unsigned int cab = 0u;                            // ca | (cb<<16), fits: <=4096 each
    #pragma unroll
    for (int b = 0; b < NB; ++b) {
        f32x4 v = xrow[b * 64 + lane];
        #pragma unroll
        for (int j = 0; j < 4; ++j) {
            unsigned int q = f2ord(v[j]);
            unsigned int lo2 = min(m1, q);
            m1 = max(m1, q);
            m2 = max(m2, lo2);
            cab += (q >= A) ? 1u : 0u;
            cab += (q >= B) ? 0x10000u : 0u;
            u[b * 4 + j] = q;
        }
    }

    // ---- wave top-2 + probe-count butterfly ----
    #pragma unroll
    for (int off = 32; off; off >>= 1) {
        unsigned int o1 = __shfl_xor(m1, off);
        unsigned int o2 = __shfl_xor(m2, off);
        cab += __shfl_xor(cab, off);                  // halves can't carry-cross
        unsigned int hi2 = max(m1, o1), lo2 = min(m1, o1);
        m2 = max(m2, max(lo2, o2));
        m1 = hi2;
    }
    const int cnt_a = (int)(cab & 0xFFFFu);
    const int cnt_b = (int)(cab >> 16);
    const float gain = 3.0f / (1.0f + expf(-(ord2f(m1) - ord2f(m2)))) + 1.0f;

    // ---- bracketed interpolation search for exact k-th-largest pattern ----
    // invariant: count(>= lo) = cnt_lo >= K > cnt_hi = count(>= hi)
    unsigned long long lo, hi;
    int cnt_lo, cnt_hi;
    if (cnt_a >= K) {
        if (cnt_b >= K) { lo = B; cnt_lo = cnt_b; hi = 0x100000000ull; cnt_hi = 0; }
        else            { lo = A; cnt_lo = cnt_a; hi = B;              cnt_hi = cnt_b; }
    } else              { lo = 0; cnt_lo = D;     hi = A;              cnt_hi = cnt_a; }

    int toggle = 0;
    while (hi - lo > 1ull && cnt_lo != K) {
        unsigned long long span = hi - lo;
        unsigned long long mid;
        if (toggle) {
            mid = lo + (span >> 1);                   // safeguard: plain bisection
        } else {
            // regula falsi: local CDF is ~linear in the ordered-uint domain
            float frac = (float)(cnt_lo - K) *
                         __builtin_amdgcn_rcpf((float)(cnt_lo - cnt_hi));
            unsigned long long step = (unsigned long long)((float)span * frac);
            if (step < 1ull)        step = 1ull;      // guarantee progress
            if (step > span - 1ull) step = span - 1ull;
            mid = lo + step;
        }
        toggle ^= 1;
        const unsigned int midu = (unsigned int)mid;
        int cnt = 0;
        #pragma unroll
        for (int j = 0; j < VPT; ++j)
            cnt += (int)__popcll(__ballot(u[j] >= midu));
        if (cnt >= K) { lo = mid; cnt_lo = cnt; }     // cnt==K exits loop
        else          { hi = mid; cnt_hi = cnt; }
    }
    const unsigned int ut = (unsigned int)lo;         // exact k-th largest pattern
    const float g = gain;

    // ---- output ----
    if (cnt_lo == K) {
        // exact-count fast path: keep iff u >= ut (no boundary ties to split)
        #pragma unroll
        for (int b = 0; b < NB; ++b) {
            f32x4 o;
            #pragma unroll
            for (int j = 0; j < 4; ++j) {
                unsigned int uu = u[b * 4 + j];
                o[j] = (uu >= ut) ? ord2f(uu) * g : 0.0f;
            }
            __builtin_nontemporal_store(o, orow + b * 64 + lane);
        }
    } else {
        // rare: exact-duplicate patterns straddle rank K -> lowest index first.
        // element global index = 256*b + 4*lane + j.
        const int needed = K - cnt_hi;                // #equals to include (>=1)
        const unsigned long long ltmask =
            (lane == 0) ? 0ull : ((~0ull) >> (64 - lane));
        int eq_before = 0;                            // equals in earlier batches
        #pragma unroll
        for (int b = 0; b < NB; ++b) {
            unsigned long long bal[4];
            #pragma unroll
            for (int j = 0; j < 4; ++j) bal[j] = __ballot(u[b * 4 + j] == ut);
            f32x4 o;
            #pragma unroll
            for (int j = 0; j < 4; ++j) {
                unsigned int uu = u[b * 4 + j];
                float f = 0.0f;
                if (uu > ut) {
                    f = ord2f(uu) * g;
                } else if (uu == ut) {
                    int r = eq_before;
                    #pragma unroll
                    for (int j2 = 0; j2 < 4; ++j2) {
                        r += (int)__popcll(bal[j2] & ltmask);     // lanes < me
                        if (j2 < j) r += (int)((bal[j2] >> lane) & 1ull);
                    }
                    if (r < needed) f = ord2f(uu) * g;
                }
                o[j] = f;
            }
            __builtin_nontemporal_store(o, orow + b * 64 + lane);
            #pragma unroll
            for (int j2 = 0; j2 < 4; ++j2)
                eq_before += (int)__popcll(bal[j2]);
        }
    }
}

extern "C" void kernel_launch(void* const* d_in, const int* in_sizes, int n_in,
                              void* d_out, int out_size, void* d_ws, size_t ws_size,
                              hipStream_t stream) {
    const float* x = (const float*)d_in[0];
    float* out = (float*)d_out;
    const int rows = in_sizes[0] / D;                 // 16384
    diffgated_topk<<<dim3((rows + 3) / 4), dim3(BLOCK), 0, stream>>>(x, out, rows);
}

// Round 3
// 445.125 us; speedup vs baseline: 1.0610x; 1.0279x over previous
//
#include <hip/hip_runtime.h>
#include <math.h>

// DiffGatedTopK: x (16384 x 4096 fp32). Per row: k=614 top-k mask, gain =
// sigmoid(top1-top2)*3+1, out = x*mask*gain.
//
// ONE ROW PER 256-THREAD BLOCK (4 waves, 16 values/lane in VGPRs as FLOATS).
// R1 post-mortem showed the old 1-wave/row layout (64 regs/lane -> AGPR
// backing, 4 waves/EU, occupancy 41%) was latency-bound: VALU 28%, HBM 29%,
// per-wave duty ~9%. Splitting the row 4-ways cuts register residency to
// ~48 VGPR -> 8 waves/EU, and 4x more waves stream memory concurrently.
//
// Hot path works directly on float values: the threshold bracket
// [0.90, 1.17] (row k-th stat is N(1.036, 0.024) for i.i.d. N(0,1) rows,
// ~5.5 sigma) is strictly positive, where IEEE float compare == ordered-bit
// compare. Probe counts for the bracket are fused into the load pass.
// Bracketed regula-falsi/bisection converges to count==K in ~3-5 passes;
// cross-wave counts merge via LDS with a parity-double-buffered count slot
// (1 barrier/iter). Bracket misses and exact-duplicate boundary ties fall
// to rare fully-general ordered-uint paths (lowest index first, matching
// jax.lax.top_k). NT stores keep the L3-resident input hot.
//
// R2 bench was an infra failure (container died twice, no profile); kernel
// audited for hang hazards: all loops strictly shrink their bracket, all
// barriers are under block-uniform control flow. Resubmitting.

#define D     4096
#define K     614            // int(4096 * 0.15)
#define BLOCK 256
#define NW    4              // waves per block = waves per row
#define NB    4              // float4 batches per lane (16 values/lane)

typedef float f32x4 __attribute__((ext_vector_type(4)));

__device__ __forceinline__ unsigned int f2ord(float f) {
    unsigned int b = __float_as_uint(f);
    return ((int)b >= 0) ? (b | 0x80000000u) : ~b;
}

__global__ __launch_bounds__(BLOCK, 8)   // 64-VGPR cap: 16 data + temps
void diffgated_topk(const float* __restrict__ x, float* __restrict__ out, int rows) {
    const int tid  = threadIdx.x;
    const int lane = tid & 63;
    const int w    = tid >> 6;
    const int row  = blockIdx.x;                      // grid == rows exactly
    const f32x4* xrow = (const f32x4*)(x + (size_t)row * D);
    f32x4*       orow = (f32x4*)(out + (size_t)row * D);

    __shared__ float        sm1[NW], sm2[NW];
    __shared__ unsigned int scab[NW];
    __shared__ int          scnt[2][NW];              // parity double-buffer
    __shared__ int          eqc[NB][NW];

    const float A = 0.90f, B = 1.17f;

    // ---- load row -> registers (floats); fused per-lane top-2 + probe counts ----
    f32x4 vv[NB];
    float m1 = -INFINITY, m2 = -INFINITY;
    unsigned int cab = 0u;                            // cntA | (cntB<<16)
    #pragma unroll
    for (int b = 0; b < NB; ++b) {
        f32x4 v = xrow[b * 256 + tid];
        vv[b] = v;
        #pragma unroll
        for (int j = 0; j < 4; ++j) {
            float q = v[j];
            float lo2 = fminf(m1, q);
            m1 = fmaxf(m1, q);
            m2 = fmaxf(m2, lo2);
            cab += (q >= A) ? 1u : 0u;
            cab += (q >= B) ? 0x10000u : 0u;
        }
    }

    // ---- wave-level top-2 + probe-count butterfly ----
    #pragma unroll
    for (int off = 32; off; off >>= 1) {
        float o1 = __shfl_xor(m1, off);
        float o2 = __shfl_xor(m2, off);
        cab += __shfl_xor(cab, off);                  // fields <=4096, no carry-cross
        float hi2 = fmaxf(m1, o1), lo2 = fminf(m1, o1);
        m2 = fmaxf(m2, fmaxf(lo2, o2));
        m1 = hi2;
    }

    // ---- cross-wave merge via LDS ----
    if (lane == 0) { sm1[w] = m1; sm2[w] = m2; scab[w] = cab; }
    __syncthreads();
    {
        float a1 = sm1[0], a2 = sm2[0];
        unsigned int c = scab[0];
        #pragma unroll
        for (int i = 1; i < NW; ++i) {
            float b1 = sm1[i], b2 = sm2[i];
            float n1 = fmaxf(a1, b1);
            float n2 = fmaxf(fminf(a1, b1), fmaxf(a2, b2));
            a1 = n1; a2 = n2; c += scab[i];
        }
        m1 = a1; m2 = a2; cab = c;
    }
    const int cnt_a = (int)(cab & 0xFFFFu);
    const int cnt_b = (int)(cab >> 16);
    const float gain = 3.0f / (1.0f + expf(-(m1 - m2))) + 1.0f;

    unsigned int ut_ord;                              // ordered k-th pattern
    int cnt_lo, cnt_hi;

    if (cnt_a >= K && cnt_b < K) {
        // ======== HOT: positive-float bit-domain search in [0.90, 1.17) ========
        unsigned int lo = __float_as_uint(A), hi = __float_as_uint(B);
        cnt_lo = cnt_a; cnt_hi = cnt_b;
        int it = 0;
        while (hi - lo > 1u && cnt_lo != K) {
            unsigned int span = hi - lo;
            unsigned int mid;
            if (it & 1) {
                mid = lo + (span >> 1);               // safeguard bisection
            } else {
                // regula falsi: local CDF ~linear in the positive-float bit domain
                float frac = (float)(cnt_lo - K) *
                             __builtin_amdgcn_rcpf((float)(cnt_lo - cnt_hi));
                unsigned int step = (unsigned int)((float)span * frac);
                if (step < 1u)        step = 1u;      // guarantee progress
                if (step > span - 1u) step = span - 1u;
                mid = lo + step;
            }
            const float midf = __uint_as_float(mid);
            int cw = 0;
            #pragma unroll
            for (int b = 0; b < NB; ++b)
                #pragma unroll
                for (int j = 0; j < 4; ++j)
                    cw += (int)__popcll(__ballot(vv[b][j] >= midf));
            const int p = it & 1;
            if (lane == 0) scnt[p][w] = cw;
            __syncthreads();                          // parity buffer: 1 barrier/iter
            int cnt = scnt[p][0] + scnt[p][1] + scnt[p][2] + scnt[p][3];
            if (cnt >= K) { lo = mid; cnt_lo = cnt; } // cnt==K exits loop
            else          { hi = mid; cnt_hi = cnt; }
            ++it;
        }
        if (cnt_lo == K) {
            // exact-count fast path: keep iff v >= t (strictly positive t)
            const float tf = __uint_as_float(lo);
            #pragma unroll
            for (int b = 0; b < NB; ++b) {
                f32x4 o;
                #pragma unroll
                for (int j = 0; j < 4; ++j) {
                    float q = vv[b][j];
                    o[j] = (q >= tf) ? q * gain : 0.0f;
                }
                __builtin_nontemporal_store(o, orow + b * 256 + tid);
            }
            return;
        }
        ut_ord = lo | 0x80000000u;                    // positive float -> ordered
    } else {
        // ======== COLD: fully-general ordered-domain bisection ========
        unsigned long long lo = 0ull, hi = 0x100000000ull;
        cnt_lo = D; cnt_hi = 0;
        int it = 0;
        while (hi - lo > 1ull && cnt_lo != K) {
            unsigned int mid = (unsigned int)((lo + hi) >> 1);
            int cw = 0;
            for (int b = 0; b < NB; ++b)
                for (int j = 0; j < 4; ++j)
                    cw += (int)__popcll(__ballot(f2ord(vv[b][j]) >= mid));
            const int p = it & 1;
            if (lane == 0) scnt[p][w] = cw;
            __syncthreads();
            int cnt = scnt[p][0] + scnt[p][1] + scnt[p][2] + scnt[p][3];
            if (cnt >= K) { lo = mid; cnt_lo = cnt; }
            else          { hi = mid; cnt_hi = cnt; }
            ++it;
        }
        ut_ord = (unsigned int)lo;
        if (cnt_lo == K) {
            #pragma unroll
            for (int b = 0; b < NB; ++b) {
                f32x4 o;
                #pragma unroll
                for (int j = 0; j < 4; ++j) {
                    float q = vv[b][j];
                    o[j] = (f2ord(q) >= ut_ord) ? q * gain : 0.0f;
                }
                __builtin_nontemporal_store(o, orow + b * 256 + tid);
            }
            return;
        }
    }

    // ======== RARE: exact-duplicate ties straddle rank K ========
    // lowest global index first (matches jax.lax.top_k). Element global
    // index = 1024*b + 256*w + 4*lane + j  (lexicographic in b, w, lane, j).
    {
        const int needed = K - cnt_hi;                // #equals to include (>=1)
        const unsigned long long ltmask =
            (lane == 0) ? 0ull : ((~0ull) >> (64 - lane));
        #pragma unroll
        for (int b = 0; b < NB; ++b) {
            int e = 0;
            #pragma unroll
            for (int j = 0; j < 4; ++j)
                e += (int)__popcll(__ballot(f2ord(vv[b][j]) == ut_ord));
            if (lane == 0) eqc[b][w] = e;
        }
        __syncthreads();
        int base = 0;                                 // equals in earlier batches
        #pragma unroll
        for (int b = 0; b < NB; ++b) {
            int pre = base;
            for (int wp = 0; wp < w; ++wp) pre += eqc[b][wp];  // earlier waves, this batch
            unsigned long long bal[4];
            #pragma unroll
            for (int j = 0; j < 4; ++j)
                bal[j] = __ballot(f2ord(vv[b][j]) == ut_ord);
            f32x4 o;
            #pragma unroll
            for (int j = 0; j < 4; ++j) {
                float q = vv[b][j];
                unsigned int uo = f2ord(q);
                float f = 0.0f;
                if (uo > ut_ord) {
                    f = q * gain;
                } else if (uo == ut_ord) {
                    int r = pre;
                    #pragma unroll
                    for (int j2 = 0; j2 < 4; ++j2) {
                        r += (int)__popcll(bal[j2] & ltmask);   // lanes < me
                        if (j2 < j) r += (int)((bal[j2] >> lane) & 1ull);
                    }
                    if (r < needed) f = q * gain;
                }
                o[j] = f;
            }
            __builtin_nontemporal_store(o, orow + b * 256 + tid);
            int tot = 0;
            #pragma unroll
            for (int wp = 0; wp < NW; ++wp) tot += eqc[b][wp];
            base += tot;
        }
    }
}

extern "C" void kernel_launch(void* const* d_in, const int* in_sizes, int n_in,
                              void* d_out, int out_size, void* d_ws, size_t ws_size,
                              hipStream_t stream) {
    const float* x = (const float*)d_in[0];
    float* out = (float*)d_out;
    const int rows = in_sizes[0] / D;                 // 16384
    diffgated_topk<<<dim3(rows), dim3(BLOCK), 0, stream>>>(x, out, rows);
}